// Round 7
// baseline (203.950 us; speedup 1.0000x reference)
//
#include <hip/hip_runtime.h>
#include <hip/hip_bf16.h>

// GroupContrast loss. Per-row reductions instead of the 8192x8192 logits:
//   dense pass:  sE_i = sum_{j != i} exp(100*acc_ij - 100)     (MFMA, full matrix)
//   group pass:  sP_i = sum_pos exp(..), sA_i = sum_pos acc    (sparse, ~1% of pairs,
//     same MFMA chain -> bitwise-identical acc, so Q = sE - sP is exact)
//   final: Z = sP/pc + (sE-sP)/nc;
//          mlpp = 100*sA/pc - 100 - log(pc) - log(Z); loss = -T*mean_valid.
// History:
//  - R3: __launch_bounds__(256,4) caps VGPR at 64 -> afr[][] spills to scratch
//    (328MB FETCH, 2x slower).
//  - R5: symmetric upper-triangle pass halved MFMA busy-time but doubled wall
//    time (per-block overhead unamortized, dead blocks) -> reverted.
//  - R6: (256,3) squeezed VGPR to 84 and regressed pg 64.6->86; group blocks at
//    grid end ran as stragglers. -> (256,2) restored, group blocks FIRST.
//  - R7: pg split into two dispatches (~35us each) as a DIAGNOSTIC: any tail
//    kernel >35us now enters rocprof top-5 (previously pg filled all 5 slots).

#define N_ROWS 8192
#define D_PAD 320
#define NG 100
#define TEMP 0.01f
#define NSPLIT 32
#define JCHUNK (N_ROWS / NSPLIT)   // 256
#define LOG2E100 144.2695041f      // 100 * log2(e)

typedef short short8v __attribute__((ext_vector_type(8)));
typedef float float4v __attribute__((ext_vector_type(4)));

__device__ __forceinline__ short f2bf(float f) {
  union { __hip_bfloat16 h; short s; } u;
  u.h = __float2bfloat16(f);
  return u.s;
}

// ---------- setup: W1/W2 -> bf16 Wt[320 n][320 k] (LDS-tiled transpose)
//            + per-block histogram partials (plain stores, no memset needed) ----------
__global__ __launch_bounds__(256) void setup_kernel(
    const float* __restrict__ W1, const float* __restrict__ W2,
    const int* __restrict__ labels,
    __hip_bfloat16* __restrict__ w1t, __hip_bfloat16* __restrict__ w2t,
    int* __restrict__ counts32)
{
  __shared__ float T[64][65];
  __shared__ int hc[NG + 1];
  int b = blockIdx.x, tid = threadIdx.x;
  if (b < 50) {                          // 25 tiles per matrix, 64x64
    int isW2 = b >= 25;
    int t5 = isW2 ? b - 25 : b;
    int k0 = (t5 / 5) * 64, n0 = (t5 % 5) * 64;
    const float* W = isW2 ? W2 : W1;
    __hip_bfloat16* dst = isW2 ? w2t : w1t;
#pragma unroll
    for (int t = 0; t < 16; ++t) {       // coalesced read along n
      int e = tid + t * 256;
      int r = e >> 6, c = e & 63;
      T[r][c] = (k0 + r < 300 && n0 + c < 300)
                  ? W[(size_t)(k0 + r) * 300 + (n0 + c)] : 0.0f;
    }
    __syncthreads();
#pragma unroll
    for (int t = 0; t < 16; ++t) {       // coalesced write along k
      int e = tid + t * 256;
      int nn = e >> 6, kk = e & 63;
      dst[(size_t)(n0 + nn) * D_PAD + (k0 + kk)] = __float2bfloat16(T[kk][nn]);
    }
  } else {                               // hist partials: block h owns 256 rows
    int h = b - 50;
    if (tid <= NG) hc[tid] = 0;
    __syncthreads();
    atomicAdd(&hc[labels[h * 256 + tid]], 1);
    __syncthreads();
    if (tid <= NG) counts32[h * (NG + 1) + tid] = hc[tid];   // plain store
  }
}

// ---------- fused MLP + rownorm: x -> fb (bf16, unit rows, padded to 320) ----------
// 512 blocks x 256 threads, 16 rows/block; wave w = n-quarter (5 n-tiles each).
// -> 2 blocks/CU, 8 waves/CU (2x R6's latency hiding). B-frags (W rows) read
// directly from global (L2-hot). 2 barriers per block.
__global__ __launch_bounds__(256, 2) void mlp_fused_kernel(
    const float* __restrict__ x, const __hip_bfloat16* __restrict__ w1t,
    const __hip_bfloat16* __restrict__ w2t, const float* __restrict__ b1,
    const float* __restrict__ b2, __hip_bfloat16* __restrict__ fb)
{
  __shared__ __align__(16) short H1[16 * D_PAD];   // 10240 B (swizzled)
  __shared__ float ssq_s[16];
  const short* W1s = (const short*)w1t;
  const short* W2s = (const short*)w2t;
  int tid = threadIdx.x;
  int lane = tid & 63, p = tid >> 6;               // p = n-quarter
  int g = lane >> 4, lc = lane & 15, sw = lc & 7;
  int i0 = blockIdx.x * 16;

  if (tid < 16) ssq_s[tid] = 0.f;

  // ---- A-frags from x rows i0+lc (fp32 -> bf16); all 4 waves load same rows
  //      (first wave pulls to L1/L2, rest hit) ----
  short8v afr[10];
  {
    const float* xp = x + (size_t)(i0 + lc) * 300;
#pragma unroll
    for (int kk = 0; kk < 10; ++kk) {
      int k0 = kk * 32 + g * 8;
      short8v v;
      if (k0 + 8 <= 300) {
        float4 a = *(const float4*)(xp + k0);
        float4 c = *(const float4*)(xp + k0 + 4);
        v[0] = f2bf(a.x); v[1] = f2bf(a.y); v[2] = f2bf(a.z); v[3] = f2bf(a.w);
        v[4] = f2bf(c.x); v[5] = f2bf(c.y); v[6] = f2bf(c.z); v[7] = f2bf(c.w);
      } else if (k0 < 300) {     // k0 == 296
        float4 a = *(const float4*)(xp + k0);
        v[0] = f2bf(a.x); v[1] = f2bf(a.y); v[2] = f2bf(a.z); v[3] = f2bf(a.w);
        v[4] = 0; v[5] = 0; v[6] = 0; v[7] = 0;
      } else {
        v = short8v{0, 0, 0, 0, 0, 0, 0, 0};
      }
      afr[kk] = v;
    }
  }

  // ---- GEMM1: h1 = relu(x @ W1 + b1) -> H1 (bf16, swizzled), B from global ----
  for (int nt = 0; nt < 5; ++nt) {
    int n = (p * 5 + nt) * 16 + lc;
    float4v acc = {0.f, 0.f, 0.f, 0.f};
    const short* wp = W1s + (size_t)n * D_PAD + g * 8;
#pragma unroll
    for (int kk = 0; kk < 10; ++kk) {
      short8v bf = *(const short8v*)(wp + kk * 32);
      acc = __builtin_amdgcn_mfma_f32_16x16x32_bf16(afr[kk], bf, acc, 0, 0, 0);
    }
    float bv = (n < 300) ? b1[n] : 0.0f;
    int q = n >> 3;
#pragma unroll
    for (int r = 0; r < 4; ++r) {
      int row = g * 4 + r;
      H1[row * D_PAD + ((q ^ (row & 7)) << 3) + (n & 7)] =
          f2bf(fmaxf(acc[r] + bv, 0.0f));
    }
  }
  __syncthreads();   // H1 complete (also orders ssq_s zeroing)

  // ---- h1 A-frags from LDS ----
  short8v hfr[10];
  {
    const short* rp = H1 + lc * D_PAD;
#pragma unroll
    for (int kk = 0; kk < 10; ++kk)
      hfr[kk] = *(const short8v*)(rp + (((g + 4 * kk) ^ sw) << 3));
  }

  // ---- GEMM2: h2 = h1 @ W2 + b2, kept in registers, B from global ----
  float4v h2a[5];
  for (int nt = 0; nt < 5; ++nt) {
    int n = (p * 5 + nt) * 16 + lc;
    float4v acc = {0.f, 0.f, 0.f, 0.f};
    const short* wp = W2s + (size_t)n * D_PAD + g * 8;
#pragma unroll
    for (int kk = 0; kk < 10; ++kk) {
      short8v bf = *(const short8v*)(wp + kk * 32);
      acc = __builtin_amdgcn_mfma_f32_16x16x32_bf16(hfr[kk], bf, acc, 0, 0, 0);
    }
    float bv = (n < 300) ? b2[n] : 0.0f;
#pragma unroll
    for (int r = 0; r < 4; ++r) acc[r] += bv;   // pad cols: W/b pads=0 -> h2=0
    h2a[nt] = acc;
  }

  // ---- row ssq: lc-shuffle reduce, combine 4 waves via LDS atomics ----
  float ss[4] = {0.f, 0.f, 0.f, 0.f};
#pragma unroll
  for (int nt = 0; nt < 5; ++nt)
#pragma unroll
    for (int r = 0; r < 4; ++r) ss[r] = fmaf(h2a[nt][r], h2a[nt][r], ss[r]);
  for (int m = 1; m < 16; m <<= 1)
#pragma unroll
    for (int r = 0; r < 4; ++r) ss[r] += __shfl_xor(ss[r], m, 64);
  if (lc == 0)
#pragma unroll
    for (int r = 0; r < 4; ++r) atomicAdd(&ssq_s[g * 4 + r], ss[r]);
  __syncthreads();
  float inv[4];
#pragma unroll
  for (int r = 0; r < 4; ++r) inv[r] = rsqrtf(ssq_s[g * 4 + r]);
#pragma unroll
  for (int nt = 0; nt < 5; ++nt) {
    int n = (p * 5 + nt) * 16 + lc;
#pragma unroll
    for (int r = 0; r < 4; ++r) {
      int row = i0 + g * 4 + r;
      fb[(size_t)row * D_PAD + n] = __float2bfloat16(h2a[nt][r] * inv[r]);
    }
  }
}

// ---------- merged: per-group sparse (b < groupCount) + dense pairwise ----------
// groupCount blocks FIRST so group stragglers overlap the dense work.
__global__ __launch_bounds__(256, 2) void pg_kernel(
    const __hip_bfloat16* __restrict__ Fb, const int* __restrict__ labels,
    float* __restrict__ partE, float* __restrict__ sPar, float* __restrict__ sAar,
    int groupCount, int denseBase)
{
  __shared__ __align__(16) short Bs[64 * D_PAD];
  __shared__ int memb[256];
  __shared__ int cnt;
  const short* Fs = (const short*)Fb;
  int tid = threadIdx.x;
  int lane = tid & 63, wave = tid >> 6;
  int g = lane >> 4, lc = lane & 15, sw = lc & 7;
  int b = blockIdx.x;

  if (b >= groupCount) {
    // ---- dense: 128 i-rows (2 strips) x one 256-col j-split ----
    int d = b - groupCount + denseBase;
    int bi = d >> 5, split = d & 31;
    int i0 = bi * 128;
    int jstart = split * JCHUNK;

    short8v afr[2][10];
    for (int s = 0; s < 2; ++s) {
      const short* ap = Fs + (size_t)(i0 + s * 64 + wave * 16 + lc) * D_PAD + g * 8;
#pragma unroll
      for (int kk = 0; kk < 10; ++kk) afr[s][kk] = *(const short8v*)(ap + kk * 32);
    }
    float sE[2][4] = {};

    for (int jt = 0; jt < JCHUNK / 64; ++jt) {
      int jb = jstart + jt * 64;
      __syncthreads();
      {
        const int4* src = (const int4*)Fs;
        int4* dst = (int4*)Bs;
#pragma unroll
        for (int t = 0; t < 10; ++t) {
          int e = tid + t * 256;
          int r = e / 40, q = e - r * 40;
          dst[r * 40 + (q ^ (r & 7))] = src[(size_t)(jb + r) * 40 + q];
        }
      }
      __syncthreads();
      for (int js = 0; js < 4; ++js) {
        float4v acc0 = {0.f, 0.f, 0.f, 0.f}, acc1 = {0.f, 0.f, 0.f, 0.f};
        const short* rowp = Bs + (js * 16 + lc) * D_PAD;
#pragma unroll
        for (int kk = 0; kk < 10; ++kk) {
          short8v bf = *(const short8v*)(rowp + (((g + 4 * kk) ^ sw) << 3));
          acc0 = __builtin_amdgcn_mfma_f32_16x16x32_bf16(afr[0][kk], bf, acc0, 0, 0, 0);
          acc1 = __builtin_amdgcn_mfma_f32_16x16x32_bf16(afr[1][kk], bf, acc1, 0, 0, 0);
        }
#pragma unroll
        for (int s = 0; s < 2; ++s) {
          float4v acc = s ? acc1 : acc0;
          bool dt = (jb == i0 + s * 64) && (js == wave);
#pragma unroll
          for (int r = 0; r < 4; ++r) {
            float e = exp2f(fmaf(acc[r], LOG2E100, -LOG2E100));
            // diagonal excluded here (cannot be reconstructed later without
            // catastrophic cancellation against the ~1e-30-scale sums)
            if (dt && lc == g * 4 + r) e = 0.0f;
            sE[s][r] += e;
          }
        }
      }
    }
    for (int m = 1; m < 16; m <<= 1)
#pragma unroll
      for (int s = 0; s < 2; ++s)
#pragma unroll
        for (int r = 0; r < 4; ++r) sE[s][r] += __shfl_xor(sE[s][r], m, 64);
    if (lc == 0)
      for (int s = 0; s < 2; ++s)
        for (int r = 0; r < 4; ++r)
          partE[split * N_ROWS + i0 + s * 64 + wave * 16 + g * 4 + r] = sE[s][r];
  } else {
    // ---- sparse per-group pass: sP_i, sA_i over same-label pairs ----
    int grp = b + 1;
    if (tid == 0) cnt = 0;
    __syncthreads();
    for (int i = tid; i < N_ROWS; i += 256)
      if (labels[i] == grp) { int pp = atomicAdd(&cnt, 1); if (pp < 256) memb[pp] = i; }
    __syncthreads();
    int c = cnt > 256 ? 256 : cnt;
    int nt = (c + 63) >> 6;
    for (int it = 0; it < nt; ++it) {
      short8v afr[10];
      {
        int islot = it * 64 + wave * 16 + lc;
        int arow = memb[islot < c ? islot : 0];
        const short* ap = Fs + (size_t)arow * D_PAD + g * 8;
#pragma unroll
        for (int kk = 0; kk < 10; ++kk) afr[kk] = *(const short8v*)(ap + kk * 32);
      }
      int iglobr[4]; bool ivalid[4];
      for (int r = 0; r < 4; ++r) {
        int islot = it * 64 + wave * 16 + g * 4 + r;
        ivalid[r] = islot < c;
        iglobr[r] = memb[islot < c ? islot : 0];
      }
      float sp[4] = {}, sa[4] = {};
      for (int jt = 0; jt < nt; ++jt) {
        __syncthreads();
        {
          const int4* src = (const int4*)Fs;
          int4* dst = (int4*)Bs;
#pragma unroll
          for (int t = 0; t < 10; ++t) {
            int e = tid + t * 256;
            int r = e / 40, q = e - r * 40;
            int jslot = jt * 64 + r;
            int grow = memb[jslot < c ? jslot : 0];
            dst[r * 40 + (q ^ (r & 7))] = src[(size_t)grow * 40 + q];
          }
        }
        __syncthreads();
        for (int js = 0; js < 4; ++js) {
          float4v acc = {0.f, 0.f, 0.f, 0.f};
          const short* rowp = Bs + (js * 16 + lc) * D_PAD;
#pragma unroll
          for (int kk = 0; kk < 10; ++kk) {
            short8v bf = *(const short8v*)(rowp + (((g + 4 * kk) ^ sw) << 3));
            acc = __builtin_amdgcn_mfma_f32_16x16x32_bf16(afr[kk], bf, acc, 0, 0, 0);
          }
          int jslot = jt * 64 + js * 16 + lc;
          bool jv = jslot < c;
          int jglob = memb[jslot < c ? jslot : 0];
#pragma unroll
          for (int r = 0; r < 4; ++r) {
            float a = acc[r];
            float e = exp2f(fmaf(a, LOG2E100, -LOG2E100));
            bool ok = jv && ivalid[r] && (jglob != iglobr[r]);
            sp[r] += ok ? e : 0.f;
            sa[r] += ok ? a : 0.f;
          }
        }
      }
      for (int m = 1; m < 16; m <<= 1)
        for (int r = 0; r < 4; ++r) {
          sp[r] += __shfl_xor(sp[r], m, 64);
          sa[r] += __shfl_xor(sa[r], m, 64);
        }
      if (lc == 0)
        for (int r = 0; r < 4; ++r)
          if (ivalid[r]) { sPar[iglobr[r]] = sp[r]; sAar[iglobr[r]] = sa[r]; }
    }
  }
}

// ---------- final_a: 32 blocks, coalesced partE combine + per-row mlpp ----------
__global__ __launch_bounds__(256) void final_a_kernel(
    const float* __restrict__ partE, const float* __restrict__ sPar,
    const float* __restrict__ sAar, const int* __restrict__ counts32,
    const int* __restrict__ labels, float* __restrict__ blk)
{
  __shared__ int cnt_s[NG + 1];
  __shared__ float rm[256], rv[256];
  int tid = threadIdx.x;
  int i = blockIdx.x * 256 + tid;
  if (tid <= NG) {
    int c = 0;
    for (int s = 0; s < 32; ++s) c += counts32[s * (NG + 1) + tid];
    cnt_s[tid] = c;
  }
  float sE = 0.f;
  for (int s = 0; s < NSPLIT; ++s) sE += partE[s * N_ROWS + i];   // coalesced
  __syncthreads();
  float M = 0.f, V = 0.f;
  int pc = cnt_s[labels[i]] - 1;
  if (pc > 0) {
    float P = sPar[i], A = sAar[i];
    float Q = sE - P;
    float pcf = (float)pc, ncf = (float)(N_ROWS - 1 - pc);
    float Z = P / pcf + Q / ncf;
    M = 100.0f * A / pcf - 100.0f - logf(pcf) - logf(Z);
    V = 1.f;
  }
  rm[tid] = M; rv[tid] = V;
  __syncthreads();
  for (int s2 = 128; s2 > 0; s2 >>= 1) {
    if (tid < s2) { rm[tid] += rm[tid + s2]; rv[tid] += rv[tid + s2]; }
    __syncthreads();
  }
  if (tid == 0) { blk[blockIdx.x] = rm[0]; blk[32 + blockIdx.x] = rv[0]; }
}

__global__ void final_b_kernel(const float* __restrict__ blk, float* __restrict__ out)
{
  int lane = threadIdx.x;   // 64 threads
  float m = (lane < 32) ? blk[lane] : 0.f;
  float v = (lane < 32) ? blk[32 + lane] : 0.f;
  for (int s = 1; s < 32; s <<= 1) { m += __shfl_xor(m, s, 64); v += __shfl_xor(v, s, 64); }
  if (lane == 0) out[0] = (v > 0.f) ? (-TEMP * m / v) : 0.f;
}

extern "C" void kernel_launch(void* const* d_in, const int* in_sizes, int n_in,
                              void* d_out, int out_size, void* d_ws, size_t ws_size,
                              hipStream_t stream)
{
  const float* x  = (const float*)d_in[0];
  const float* W1 = (const float*)d_in[1];
  const float* b1 = (const float*)d_in[2];
  const float* W2 = (const float*)d_in[3];
  const float* b2 = (const float*)d_in[4];
  const int* labels = (const int*)d_in[5];

  char* ws = (char*)d_ws;
  __hip_bfloat16* fb    = (__hip_bfloat16*)(ws);            // 5,242,880
  __hip_bfloat16* w1t   = (__hip_bfloat16*)(ws + 5242880);  // 204,800
  __hip_bfloat16* w2t   = (__hip_bfloat16*)(ws + 5447680);  // 204,800
  int*         counts32 = (int*)(ws + 5652480);             // 12,928 (pad 13,056)
  float*        partE   = (float*)(ws + 5665536);           // 1,048,576
  float*        sPar    = (float*)(ws + 6714112);           // 32,768
  float*        sAar    = (float*)(ws + 6746880);           // 32,768
  float*        blk     = (float*)(ws + 6779648);           // 256

  setup_kernel<<<82, 256, 0, stream>>>(W1, W2, labels, w1t, w2t, counts32);
  mlp_fused_kernel<<<512, 256, 0, stream>>>(x, w1t, w2t, b1, b2, fb);
  pg_kernel<<<NG + 1024, 256, 0, stream>>>(fb, labels, partE, sPar, sAar, NG, 0);
  pg_kernel<<<1024, 256, 0, stream>>>(fb, labels, partE, sPar, sAar, 0, 1024);
  final_a_kernel<<<32, 256, 0, stream>>>(partE, sPar, sAar, counts32, labels, blk);
  final_b_kernel<<<1, 64, 0, stream>>>(blk, (float*)d_out);
}

// Round 8
// 182.221 us; speedup vs baseline: 1.1192x; 1.1192x over previous
//
#include <hip/hip_runtime.h>
#include <hip/hip_bf16.h>

// GroupContrast loss. Per-row reductions instead of the 8192x8192 logits:
//   dense pass:  sE_i = sum_{j != i} exp(100*acc_ij - 100)     (MFMA, full matrix)
//   group pass:  sP_i = sum_pos exp(..), sA_i = sum_pos acc    (sparse, ~1% of pairs,
//     same MFMA chain -> bitwise-identical acc, so Q = sE - sP is exact)
//   final: Z = sP/pc + (sE-sP)/nc;
//          mlpp = 100*sA/pc - 100 - log(pc) - log(Z); loss = -T*mean_valid.
// History (hard-won):
//  - R3: __launch_bounds__(256,4) caps VGPR at 64 -> afr[][] spills to scratch
//    (328MB FETCH, 2x slower). (256,2) is the safe setting.
//  - R5: symmetric upper-triangle pass halved MFMA busy-time but doubled wall
//    time (per-block overhead unamortized, dead blocks) -> reverted.
//  - R6/R7: ANY merge of group logic into the dense kernel (branch + runtime
//    grid args) degrades codegen (VGPR 108->84/88, MfmaUtil 26->13%, ~2x
//    slower dense blocks). Dense kernel must stay standalone and branch-free.
//  - R8: staging via __builtin_amdgcn_global_load_lds(16B); swizzle applied to
//    the SOURCE address (LDS side must be contiguous base+lane*16).

#define N_ROWS 8192
#define D_PAD 320
#define NG 100
#define TEMP 0.01f
#define NSPLIT 32
#define JCHUNK (N_ROWS / NSPLIT)   // 256
#define LOG2E100 144.2695041f      // 100 * log2(e)

typedef short short8v __attribute__((ext_vector_type(8)));
typedef float float4v __attribute__((ext_vector_type(4)));

__device__ __forceinline__ short f2bf(float f) {
  union { __hip_bfloat16 h; short s; } u;
  u.h = __float2bfloat16(f);
  return u.s;
}

// ---------- setup: W1/W2 -> bf16 Wt[320 n][320 k] (LDS-tiled transpose)
//            + per-block histogram partials (plain stores, no memset needed) ----------
__global__ __launch_bounds__(256) void setup_kernel(
    const float* __restrict__ W1, const float* __restrict__ W2,
    const int* __restrict__ labels,
    __hip_bfloat16* __restrict__ w1t, __hip_bfloat16* __restrict__ w2t,
    int* __restrict__ counts32)
{
  __shared__ float T[64][65];
  __shared__ int hc[NG + 1];
  int b = blockIdx.x, tid = threadIdx.x;
  if (b < 50) {                          // 25 tiles per matrix, 64x64
    int isW2 = b >= 25;
    int t5 = isW2 ? b - 25 : b;
    int k0 = (t5 / 5) * 64, n0 = (t5 % 5) * 64;
    const float* W = isW2 ? W2 : W1;
    __hip_bfloat16* dst = isW2 ? w2t : w1t;
#pragma unroll
    for (int t = 0; t < 16; ++t) {       // coalesced read along n
      int e = tid + t * 256;
      int r = e >> 6, c = e & 63;
      T[r][c] = (k0 + r < 300 && n0 + c < 300)
                  ? W[(size_t)(k0 + r) * 300 + (n0 + c)] : 0.0f;
    }
    __syncthreads();
#pragma unroll
    for (int t = 0; t < 16; ++t) {       // coalesced write along k
      int e = tid + t * 256;
      int nn = e >> 6, kk = e & 63;
      dst[(size_t)(n0 + nn) * D_PAD + (k0 + kk)] = __float2bfloat16(T[kk][nn]);
    }
  } else {                               // hist partials: block h owns 256 rows
    int h = b - 50;
    if (tid <= NG) hc[tid] = 0;
    __syncthreads();
    atomicAdd(&hc[labels[h * 256 + tid]], 1);
    __syncthreads();
    if (tid <= NG) counts32[h * (NG + 1) + tid] = hc[tid];   // plain store
  }
}

// ---------- fused MLP + rownorm: x -> fb (bf16, unit rows, padded to 320) ----------
// 512 blocks x 256 threads, 16 rows/block; wave w = n-quarter (5 n-tiles each).
__global__ __launch_bounds__(256, 2) void mlp_fused_kernel(
    const float* __restrict__ x, const __hip_bfloat16* __restrict__ w1t,
    const __hip_bfloat16* __restrict__ w2t, const float* __restrict__ b1,
    const float* __restrict__ b2, __hip_bfloat16* __restrict__ fb)
{
  __shared__ __align__(16) short H1[16 * D_PAD];   // 10240 B (swizzled)
  __shared__ float ssq_s[16];
  const short* W1s = (const short*)w1t;
  const short* W2s = (const short*)w2t;
  int tid = threadIdx.x;
  int lane = tid & 63, p = tid >> 6;               // p = n-quarter
  int g = lane >> 4, lc = lane & 15, sw = lc & 7;
  int i0 = blockIdx.x * 16;

  if (tid < 16) ssq_s[tid] = 0.f;

  // ---- A-frags from x rows i0+lc (fp32 -> bf16) ----
  short8v afr[10];
  {
    const float* xp = x + (size_t)(i0 + lc) * 300;
#pragma unroll
    for (int kk = 0; kk < 10; ++kk) {
      int k0 = kk * 32 + g * 8;
      short8v v;
      if (k0 + 8 <= 300) {
        float4 a = *(const float4*)(xp + k0);
        float4 c = *(const float4*)(xp + k0 + 4);
        v[0] = f2bf(a.x); v[1] = f2bf(a.y); v[2] = f2bf(a.z); v[3] = f2bf(a.w);
        v[4] = f2bf(c.x); v[5] = f2bf(c.y); v[6] = f2bf(c.z); v[7] = f2bf(c.w);
      } else if (k0 < 300) {     // k0 == 296
        float4 a = *(const float4*)(xp + k0);
        v[0] = f2bf(a.x); v[1] = f2bf(a.y); v[2] = f2bf(a.z); v[3] = f2bf(a.w);
        v[4] = 0; v[5] = 0; v[6] = 0; v[7] = 0;
      } else {
        v = short8v{0, 0, 0, 0, 0, 0, 0, 0};
      }
      afr[kk] = v;
    }
  }

  // ---- GEMM1: h1 = relu(x @ W1 + b1) -> H1 (bf16, swizzled), B from global ----
  for (int nt = 0; nt < 5; ++nt) {
    int n = (p * 5 + nt) * 16 + lc;
    float4v acc = {0.f, 0.f, 0.f, 0.f};
    const short* wp = W1s + (size_t)n * D_PAD + g * 8;
#pragma unroll
    for (int kk = 0; kk < 10; ++kk) {
      short8v bf = *(const short8v*)(wp + kk * 32);
      acc = __builtin_amdgcn_mfma_f32_16x16x32_bf16(afr[kk], bf, acc, 0, 0, 0);
    }
    float bv = (n < 300) ? b1[n] : 0.0f;
    int q = n >> 3;
#pragma unroll
    for (int r = 0; r < 4; ++r) {
      int row = g * 4 + r;
      H1[row * D_PAD + ((q ^ (row & 7)) << 3) + (n & 7)] =
          f2bf(fmaxf(acc[r] + bv, 0.0f));
    }
  }
  __syncthreads();   // H1 complete (also orders ssq_s zeroing)

  // ---- h1 A-frags from LDS ----
  short8v hfr[10];
  {
    const short* rp = H1 + lc * D_PAD;
#pragma unroll
    for (int kk = 0; kk < 10; ++kk)
      hfr[kk] = *(const short8v*)(rp + (((g + 4 * kk) ^ sw) << 3));
  }

  // ---- GEMM2: h2 = h1 @ W2 + b2, kept in registers, B from global ----
  float4v h2a[5];
  for (int nt = 0; nt < 5; ++nt) {
    int n = (p * 5 + nt) * 16 + lc;
    float4v acc = {0.f, 0.f, 0.f, 0.f};
    const short* wp = W2s + (size_t)n * D_PAD + g * 8;
#pragma unroll
    for (int kk = 0; kk < 10; ++kk) {
      short8v bf = *(const short8v*)(wp + kk * 32);
      acc = __builtin_amdgcn_mfma_f32_16x16x32_bf16(hfr[kk], bf, acc, 0, 0, 0);
    }
    float bv = (n < 300) ? b2[n] : 0.0f;
#pragma unroll
    for (int r = 0; r < 4; ++r) acc[r] += bv;   // pad cols: W/b pads=0 -> h2=0
    h2a[nt] = acc;
  }

  // ---- row ssq: lc-shuffle reduce, combine 4 waves via LDS atomics ----
  float ss[4] = {0.f, 0.f, 0.f, 0.f};
#pragma unroll
  for (int nt = 0; nt < 5; ++nt)
#pragma unroll
    for (int r = 0; r < 4; ++r) ss[r] = fmaf(h2a[nt][r], h2a[nt][r], ss[r]);
  for (int m = 1; m < 16; m <<= 1)
#pragma unroll
    for (int r = 0; r < 4; ++r) ss[r] += __shfl_xor(ss[r], m, 64);
  if (lc == 0)
#pragma unroll
    for (int r = 0; r < 4; ++r) atomicAdd(&ssq_s[g * 4 + r], ss[r]);
  __syncthreads();
  float inv[4];
#pragma unroll
  for (int r = 0; r < 4; ++r) inv[r] = rsqrtf(ssq_s[g * 4 + r]);
#pragma unroll
  for (int nt = 0; nt < 5; ++nt) {
    int n = (p * 5 + nt) * 16 + lc;
#pragma unroll
    for (int r = 0; r < 4; ++r) {
      int row = i0 + g * 4 + r;
      fb[(size_t)row * D_PAD + n] = __float2bfloat16(h2a[nt][r] * inv[r]);
    }
  }
}

// ---------- sparse per-group pass: sP_i, sA_i over same-label pairs ----------
// Standalone (R6/R7 lesson: merging this into the dense kernel ruins codegen).
__global__ __launch_bounds__(256) void group_kernel(
    const __hip_bfloat16* __restrict__ Fb, const int* __restrict__ labels,
    float* __restrict__ sPar, float* __restrict__ sAar)
{
  __shared__ __align__(16) short Bs[64 * D_PAD];
  __shared__ int memb[256];
  __shared__ int cnt;
  const short* Fs = (const short*)Fb;
  int tid = threadIdx.x;
  int lane = tid & 63, wave = tid >> 6;
  int g = lane >> 4, lc = lane & 15, sw = lc & 7;
  int grp = blockIdx.x + 1;
  if (tid == 0) cnt = 0;
  __syncthreads();
  for (int i = tid; i < N_ROWS; i += 256)
    if (labels[i] == grp) { int p = atomicAdd(&cnt, 1); if (p < 256) memb[p] = i; }
  __syncthreads();
  int c = cnt > 256 ? 256 : cnt;
  int nt = (c + 63) >> 6;
  for (int it = 0; it < nt; ++it) {
    short8v afr[10];
    {
      int islot = it * 64 + wave * 16 + lc;
      int arow = memb[islot < c ? islot : 0];
      const short* ap = Fs + (size_t)arow * D_PAD + g * 8;
#pragma unroll
      for (int kk = 0; kk < 10; ++kk) afr[kk] = *(const short8v*)(ap + kk * 32);
    }
    int iglobr[4]; bool ivalid[4];
    for (int r = 0; r < 4; ++r) {
      int islot = it * 64 + wave * 16 + g * 4 + r;
      ivalid[r] = islot < c;
      iglobr[r] = memb[islot < c ? islot : 0];
    }
    float sp[4] = {}, sa[4] = {};
    for (int jt = 0; jt < nt; ++jt) {
      __syncthreads();
      {
        const int4* src = (const int4*)Fs;
        int4* dst = (int4*)Bs;
#pragma unroll
        for (int t = 0; t < 10; ++t) {
          int e = tid + t * 256;
          int r = e / 40, q = e - r * 40;
          int jslot = jt * 64 + r;
          int grow = memb[jslot < c ? jslot : 0];
          dst[r * 40 + (q ^ (r & 7))] = src[(size_t)grow * 40 + q];
        }
      }
      __syncthreads();
      for (int js = 0; js < 4; ++js) {
        float4v acc = {0.f, 0.f, 0.f, 0.f};
        const short* rowp = Bs + (js * 16 + lc) * D_PAD;
#pragma unroll
        for (int kk = 0; kk < 10; ++kk) {
          short8v bf = *(const short8v*)(rowp + (((g + 4 * kk) ^ sw) << 3));
          acc = __builtin_amdgcn_mfma_f32_16x16x32_bf16(afr[kk], bf, acc, 0, 0, 0);
        }
        int jslot = jt * 64 + js * 16 + lc;
        bool jv = jslot < c;
        int jglob = memb[jslot < c ? jslot : 0];
#pragma unroll
        for (int r = 0; r < 4; ++r) {
          float a = acc[r];
          float e = exp2f(fmaf(a, LOG2E100, -LOG2E100));
          bool ok = jv && ivalid[r] && (jglob != iglobr[r]);
          sp[r] += ok ? e : 0.f;
          sa[r] += ok ? a : 0.f;
        }
      }
    }
    for (int m = 1; m < 16; m <<= 1)
      for (int r = 0; r < 4; ++r) {
        sp[r] += __shfl_xor(sp[r], m, 64);
        sa[r] += __shfl_xor(sa[r], m, 64);
      }
    if (lc == 0)
      for (int r = 0; r < 4; ++r)
        if (ivalid[r]) { sPar[iglobr[r]] = sp[r]; sAar[iglobr[r]] = sa[r]; }
  }
}

// ---------- dense pairwise: sE only (standalone, branch-free) ----------
// Staging via global_load_lds(16B): LDS side is contiguous base+lane*16;
// the XOR swizzle is applied to the per-lane SOURCE address instead.
__global__ __launch_bounds__(256, 2) void pairwise_kernel(
    const __hip_bfloat16* __restrict__ Fb, float* __restrict__ partE)
{
  __shared__ __align__(16) short Bs[64 * D_PAD];
  const short* Fs = (const short*)Fb;
  int tid = threadIdx.x;
  int lane = tid & 63, wave = tid >> 6;
  int g = lane >> 4, lc = lane & 15, sw = lc & 7;
  int i0 = blockIdx.x * 128;
  int split = blockIdx.y;
  int jstart = split * JCHUNK;

  short8v afr[2][10];
  for (int s = 0; s < 2; ++s) {
    const short* ap = Fs + (size_t)(i0 + s * 64 + wave * 16 + lc) * D_PAD + g * 8;
#pragma unroll
    for (int kk = 0; kk < 10; ++kk) afr[s][kk] = *(const short8v*)(ap + kk * 32);
  }
  float sE[2][4] = {};

  for (int jt = 0; jt < JCHUNK / 64; ++jt) {
    int jb = jstart + jt * 64;
    __syncthreads();
    {
      // LDS slot e=(r,q') receives src(jb+r, q'^(r&7)) -> swizzled layout,
      // contiguous LDS destinations as global_load_lds requires.
      const int4* src = (const int4*)Fs;
#pragma unroll
      for (int t = 0; t < 10; ++t) {
        int e = tid + t * 256;
        int r = e / 40, q = e - r * 40;
        int qs = q ^ (r & 7);
        __builtin_amdgcn_global_load_lds(
            (const __attribute__((address_space(1))) void*)(src + (size_t)(jb + r) * 40 + qs),
            (__attribute__((address_space(3))) void*)((int4*)Bs + e),
            16, 0, 0);
      }
    }
    __syncthreads();
    for (int js = 0; js < 4; ++js) {
      float4v acc0 = {0.f, 0.f, 0.f, 0.f}, acc1 = {0.f, 0.f, 0.f, 0.f};
      const short* rowp = Bs + (js * 16 + lc) * D_PAD;
#pragma unroll
      for (int kk = 0; kk < 10; ++kk) {
        short8v bf = *(const short8v*)(rowp + (((g + 4 * kk) ^ sw) << 3));
        acc0 = __builtin_amdgcn_mfma_f32_16x16x32_bf16(afr[0][kk], bf, acc0, 0, 0, 0);
        acc1 = __builtin_amdgcn_mfma_f32_16x16x32_bf16(afr[1][kk], bf, acc1, 0, 0, 0);
      }
#pragma unroll
      for (int s = 0; s < 2; ++s) {
        float4v acc = s ? acc1 : acc0;
        bool dt = (jb == i0 + s * 64) && (js == wave);
#pragma unroll
        for (int r = 0; r < 4; ++r) {
          float e = exp2f(fmaf(acc[r], LOG2E100, -LOG2E100));
          // diagonal excluded here (cannot be reconstructed later without
          // catastrophic cancellation against the ~1e-30-scale sums)
          if (dt && lc == g * 4 + r) e = 0.0f;
          sE[s][r] += e;
        }
      }
    }
  }
  for (int m = 1; m < 16; m <<= 1)
#pragma unroll
    for (int s = 0; s < 2; ++s)
#pragma unroll
      for (int r = 0; r < 4; ++r) sE[s][r] += __shfl_xor(sE[s][r], m, 64);
  if (lc == 0)
    for (int s = 0; s < 2; ++s)
      for (int r = 0; r < 4; ++r)
        partE[split * N_ROWS + i0 + s * 64 + wave * 16 + g * 4 + r] = sE[s][r];
}

// ---------- final_a: 32 blocks, coalesced partE combine + per-row mlpp ----------
__global__ __launch_bounds__(256) void final_a_kernel(
    const float* __restrict__ partE, const float* __restrict__ sPar,
    const float* __restrict__ sAar, const int* __restrict__ counts32,
    const int* __restrict__ labels, float* __restrict__ blk)
{
  __shared__ int cnt_s[NG + 1];
  __shared__ float rm[256], rv[256];
  int tid = threadIdx.x;
  int i = blockIdx.x * 256 + tid;
  if (tid <= NG) {
    int c = 0;
    for (int s = 0; s < 32; ++s) c += counts32[s * (NG + 1) + tid];
    cnt_s[tid] = c;
  }
  float sE = 0.f;
  for (int s = 0; s < NSPLIT; ++s) sE += partE[s * N_ROWS + i];   // coalesced
  __syncthreads();
  float M = 0.f, V = 0.f;
  int pc = cnt_s[labels[i]] - 1;
  if (pc > 0) {
    float P = sPar[i], A = sAar[i];
    float Q = sE - P;
    float pcf = (float)pc, ncf = (float)(N_ROWS - 1 - pc);
    float Z = P / pcf + Q / ncf;
    M = 100.0f * A / pcf - 100.0f - logf(pcf) - logf(Z);
    V = 1.f;
  }
  rm[tid] = M; rv[tid] = V;
  __syncthreads();
  for (int s2 = 128; s2 > 0; s2 >>= 1) {
    if (tid < s2) { rm[tid] += rm[tid + s2]; rv[tid] += rv[tid + s2]; }
    __syncthreads();
  }
  if (tid == 0) { blk[blockIdx.x] = rm[0]; blk[32 + blockIdx.x] = rv[0]; }
}

__global__ void final_b_kernel(const float* __restrict__ blk, float* __restrict__ out)
{
  int lane = threadIdx.x;   // 64 threads
  float m = (lane < 32) ? blk[lane] : 0.f;
  float v = (lane < 32) ? blk[32 + lane] : 0.f;
  for (int s = 1; s < 32; s <<= 1) { m += __shfl_xor(m, s, 64); v += __shfl_xor(v, s, 64); }
  if (lane == 0) out[0] = (v > 0.f) ? (-TEMP * m / v) : 0.f;
}

extern "C" void kernel_launch(void* const* d_in, const int* in_sizes, int n_in,
                              void* d_out, int out_size, void* d_ws, size_t ws_size,
                              hipStream_t stream)
{
  const float* x  = (const float*)d_in[0];
  const float* W1 = (const float*)d_in[1];
  const float* b1 = (const float*)d_in[2];
  const float* W2 = (const float*)d_in[3];
  const float* b2 = (const float*)d_in[4];
  const int* labels = (const int*)d_in[5];

  char* ws = (char*)d_ws;
  __hip_bfloat16* fb    = (__hip_bfloat16*)(ws);            // 5,242,880
  __hip_bfloat16* w1t   = (__hip_bfloat16*)(ws + 5242880);  // 204,800
  __hip_bfloat16* w2t   = (__hip_bfloat16*)(ws + 5447680);  // 204,800
  int*         counts32 = (int*)(ws + 5652480);             // 12,928 (pad 13,056)
  float*        partE   = (float*)(ws + 5665536);           // 1,048,576
  float*        sPar    = (float*)(ws + 6714112);           // 32,768
  float*        sAar    = (float*)(ws + 6746880);           // 32,768
  float*        blk     = (float*)(ws + 6779648);           // 256

  setup_kernel<<<82, 256, 0, stream>>>(W1, W2, labels, w1t, w2t, counts32);
  mlp_fused_kernel<<<512, 256, 0, stream>>>(x, w1t, w2t, b1, b2, fb);
  group_kernel<<<NG, 256, 0, stream>>>(fb, labels, sPar, sAar);
  pairwise_kernel<<<dim3(64, NSPLIT), 256, 0, stream>>>(fb, partE);
  final_a_kernel<<<32, 256, 0, stream>>>(partE, sPar, sAar, counts32, labels, blk);
  final_b_kernel<<<1, 64, 0, stream>>>(blk, (float*)d_out);
}

// Round 9
// 175.033 us; speedup vs baseline: 1.1652x; 1.0411x over previous
//
#include <hip/hip_runtime.h>
#include <hip/hip_bf16.h>

// GroupContrast loss. Per-row reductions instead of the 8192x8192 logits:
//   dense pass:  sE_i = sum_{j != i} exp(100*acc_ij - 100)     (fp8 MFMA, full matrix)
//   group pass:  sP_i = sum_pos exp(..), sA_i = sum_pos acc    (sparse, ~1% of pairs,
//     same fp8 data + same MFMA chain -> bitwise-identical acc, Q = sE - sP exact)
//   final: Z = sP/pc + (sE-sP)/nc;
//          mlpp = 100*sA/pc - 100 - log(pc) - log(Z); loss = -T*mean_valid.
// History (hard-won):
//  - R3: __launch_bounds__(256,4) caps VGPR at 64 -> spill to scratch (328MB FETCH).
//    Empirical: arg2=2 -> cap ~128 (safe), 3 -> 84, 4 -> 64.
//  - R5: symmetric upper-triangle halved MFMA work, doubled wall time -> reverted.
//  - R6/R7: merging group logic into dense kernel ruins codegen (MfmaUtil 26->13%).
//    Dense kernel stays standalone, branch-free, compile-time grid constants.
//  - R8: pipe accounting closes: LDS-read 25.6 + MFMA 20.7 + VALU 17 = 63us
//    measured -> pipes SUM (no overlap, 2 blocks/CU). R9: fp8 halves LDS bytes
//    and LDS footprint (21.5KB tile, 336-B padded stride) -> 4 blocks/CU.
//  - R7<->R8 delta: standalone group_kernel ~40us (serial scalar label scan).
//    R9: ballot-based deterministic scan + it-split over blockIdx.y.

#define N_ROWS 8192
#define NG 100
#define TEMP 0.01f
#define NSPLIT 32
#define JCHUNK (N_ROWS / NSPLIT)   // 256
#define LOG2E100 144.2695041f      // 100 * log2(e)
#define FB_STRIDE 320              // fp8 bytes per row (300 padded)
#define LDS_STRIDE 336             // +16B pad -> <=2-way LDS banks on b64 reads

typedef short short8v __attribute__((ext_vector_type(8)));
typedef float float4v __attribute__((ext_vector_type(4)));

__device__ __forceinline__ short f2bf(float f) {
  union { __hip_bfloat16 h; short s; } u;
  u.h = __float2bfloat16(f);
  return u.s;
}

// ---------- setup: W1/W2 -> bf16 Wt[320 n][320 k] (LDS-tiled transpose)
//            + per-block histogram partials (plain stores, no memset needed) ----------
__global__ __launch_bounds__(256) void setup_kernel(
    const float* __restrict__ W1, const float* __restrict__ W2,
    const int* __restrict__ labels,
    __hip_bfloat16* __restrict__ w1t, __hip_bfloat16* __restrict__ w2t,
    int* __restrict__ counts32)
{
  __shared__ float T[64][65];
  __shared__ int hc[NG + 1];
  int b = blockIdx.x, tid = threadIdx.x;
  if (b < 50) {                          // 25 tiles per matrix, 64x64
    int isW2 = b >= 25;
    int t5 = isW2 ? b - 25 : b;
    int k0 = (t5 / 5) * 64, n0 = (t5 % 5) * 64;
    const float* W = isW2 ? W2 : W1;
    __hip_bfloat16* dst = isW2 ? w2t : w1t;
#pragma unroll
    for (int t = 0; t < 16; ++t) {       // coalesced read along n
      int e = tid + t * 256;
      int r = e >> 6, c = e & 63;
      T[r][c] = (k0 + r < 300 && n0 + c < 300)
                  ? W[(size_t)(k0 + r) * 300 + (n0 + c)] : 0.0f;
    }
    __syncthreads();
#pragma unroll
    for (int t = 0; t < 16; ++t) {       // coalesced write along k
      int e = tid + t * 256;
      int nn = e >> 6, kk = e & 63;
      dst[(size_t)(n0 + nn) * 320 + (k0 + kk)] = __float2bfloat16(T[kk][nn]);
    }
  } else {                               // hist partials: block h owns 256 rows
    int h = b - 50;
    if (tid <= NG) hc[tid] = 0;
    __syncthreads();
    atomicAdd(&hc[labels[h * 256 + tid]], 1);
    __syncthreads();
    if (tid <= NG) counts32[h * (NG + 1) + tid] = hc[tid];   // plain store
  }
}

// ---------- fused MLP + rownorm: x -> fb (fp8 e4m3, unit rows, padded to 320) ----------
// 512 blocks x 256 threads, 16 rows/block; wave w = n-quarter (5 n-tiles each).
__global__ __launch_bounds__(256, 2) void mlp_fused_kernel(
    const float* __restrict__ x, const __hip_bfloat16* __restrict__ w1t,
    const __hip_bfloat16* __restrict__ w2t, const float* __restrict__ b1,
    const float* __restrict__ b2, unsigned char* __restrict__ fb)
{
  __shared__ __align__(16) short H1[16 * 320];     // 10240 B (swizzled)
  __shared__ float ssq_s[16];
  const short* W1s = (const short*)w1t;
  const short* W2s = (const short*)w2t;
  int tid = threadIdx.x;
  int lane = tid & 63, p = tid >> 6;               // p = n-quarter
  int g = lane >> 4, lc = lane & 15, sw = lc & 7;
  int i0 = blockIdx.x * 16;

  if (tid < 16) ssq_s[tid] = 0.f;

  // ---- A-frags from x rows i0+lc (fp32 -> bf16) ----
  short8v afr[10];
  {
    const float* xp = x + (size_t)(i0 + lc) * 300;
#pragma unroll
    for (int kk = 0; kk < 10; ++kk) {
      int k0 = kk * 32 + g * 8;
      short8v v;
      if (k0 + 8 <= 300) {
        float4 a = *(const float4*)(xp + k0);
        float4 c = *(const float4*)(xp + k0 + 4);
        v[0] = f2bf(a.x); v[1] = f2bf(a.y); v[2] = f2bf(a.z); v[3] = f2bf(a.w);
        v[4] = f2bf(c.x); v[5] = f2bf(c.y); v[6] = f2bf(c.z); v[7] = f2bf(c.w);
      } else if (k0 < 300) {     // k0 == 296
        float4 a = *(const float4*)(xp + k0);
        v[0] = f2bf(a.x); v[1] = f2bf(a.y); v[2] = f2bf(a.z); v[3] = f2bf(a.w);
        v[4] = 0; v[5] = 0; v[6] = 0; v[7] = 0;
      } else {
        v = short8v{0, 0, 0, 0, 0, 0, 0, 0};
      }
      afr[kk] = v;
    }
  }

  // ---- GEMM1: h1 = relu(x @ W1 + b1) -> H1 (bf16, swizzled), B from global ----
  for (int nt = 0; nt < 5; ++nt) {
    int n = (p * 5 + nt) * 16 + lc;
    float4v acc = {0.f, 0.f, 0.f, 0.f};
    const short* wp = W1s + (size_t)n * 320 + g * 8;
#pragma unroll
    for (int kk = 0; kk < 10; ++kk) {
      short8v bf = *(const short8v*)(wp + kk * 32);
      acc = __builtin_amdgcn_mfma_f32_16x16x32_bf16(afr[kk], bf, acc, 0, 0, 0);
    }
    float bv = (n < 300) ? b1[n] : 0.0f;
    int q = n >> 3;
#pragma unroll
    for (int r = 0; r < 4; ++r) {
      int row = g * 4 + r;
      H1[row * 320 + ((q ^ (row & 7)) << 3) + (n & 7)] =
          f2bf(fmaxf(acc[r] + bv, 0.0f));
    }
  }
  __syncthreads();   // H1 complete (also orders ssq_s zeroing)

  // ---- h1 A-frags from LDS ----
  short8v hfr[10];
  {
    const short* rp = H1 + lc * 320;
#pragma unroll
    for (int kk = 0; kk < 10; ++kk)
      hfr[kk] = *(const short8v*)(rp + (((g + 4 * kk) ^ sw) << 3));
  }

  // ---- GEMM2: h2 = h1 @ W2 + b2, kept in registers, B from global ----
  float4v h2a[5];
  for (int nt = 0; nt < 5; ++nt) {
    int n = (p * 5 + nt) * 16 + lc;
    float4v acc = {0.f, 0.f, 0.f, 0.f};
    const short* wp = W2s + (size_t)n * 320 + g * 8;
#pragma unroll
    for (int kk = 0; kk < 10; ++kk) {
      short8v bf = *(const short8v*)(wp + kk * 32);
      acc = __builtin_amdgcn_mfma_f32_16x16x32_bf16(hfr[kk], bf, acc, 0, 0, 0);
    }
    float bv = (n < 300) ? b2[n] : 0.0f;
#pragma unroll
    for (int r = 0; r < 4; ++r) acc[r] += bv;   // pad cols: W/b pads=0 -> h2=0
    h2a[nt] = acc;
  }

  // ---- row ssq: lc-shuffle reduce, combine 4 waves via LDS atomics ----
  float ss[4] = {0.f, 0.f, 0.f, 0.f};
#pragma unroll
  for (int nt = 0; nt < 5; ++nt)
#pragma unroll
    for (int r = 0; r < 4; ++r) ss[r] = fmaf(h2a[nt][r], h2a[nt][r], ss[r]);
  for (int m = 1; m < 16; m <<= 1)
#pragma unroll
    for (int r = 0; r < 4; ++r) ss[r] += __shfl_xor(ss[r], m, 64);
  if (lc == 0)
#pragma unroll
    for (int r = 0; r < 4; ++r) atomicAdd(&ssq_s[g * 4 + r], ss[r]);
  __syncthreads();
  float inv[4];
#pragma unroll
  for (int r = 0; r < 4; ++r) inv[r] = rsqrtf(ssq_s[g * 4 + r]);
#pragma unroll
  for (int nt = 0; nt < 5; ++nt) {
    int n = (p * 5 + nt) * 16 + lc;
#pragma unroll
    for (int r = 0; r < 4; ++r) {
      int row = i0 + g * 4 + r;
      float v = h2a[nt][r] * inv[r];
      int pk = __builtin_amdgcn_cvt_pk_fp8_f32(v, v, 0, false);  // OCP e4m3 on gfx950
      fb[(size_t)row * FB_STRIDE + n] = (unsigned char)(pk & 0xFF);
    }
  }
}

// ---------- sparse per-group pass: sP_i, sA_i over same-label pairs (fp8) ----------
// grid (NG, 2): blockIdx.y strides the it-loop (halves the straggler).
// Member list built DETERMINISTICALLY (ballot scan by wave 0) so both y-blocks
// see identical memb ordering -> disjoint, complete i-coverage.
__global__ __launch_bounds__(256) void group_kernel(
    const unsigned char* __restrict__ Fb, const int* __restrict__ labels,
    float* __restrict__ sPar, float* __restrict__ sAar)
{
  __shared__ __align__(16) unsigned char Bs[64 * LDS_STRIDE];
  __shared__ int memb[256];
  __shared__ int cnt;
  int tid = threadIdx.x;
  int lane = tid & 63, wave = tid >> 6;
  int g = lane >> 4, lc = lane & 15;
  int grp = blockIdx.x + 1;

  if (wave == 0) {                       // deterministic ballot-compaction scan
    int base = 0;
    for (int t = 0; t < 32; ++t) {
      int4 L = ((const int4*)labels)[t * 64 + lane];
      int rb = (t * 64 + lane) * 4;
      int comp[4] = {L.x, L.y, L.z, L.w};
#pragma unroll
      for (int c4 = 0; c4 < 4; ++c4) {
        unsigned long long m = __ballot(comp[c4] == grp);
        if (comp[c4] == grp) {
          int pp = base + __popcll(m & ((1ull << lane) - 1ull));
          if (pp < 256) memb[pp] = rb + c4;
        }
        base += __popcll(m);
      }
    }
    if (lane == 0) cnt = base > 256 ? 256 : base;
  }
  __syncthreads();
  int c = cnt;
  int nt = (c + 63) >> 6;
  for (int it = blockIdx.y; it < nt; it += 2) {
    long afr[10];
    {
      int islot = it * 64 + wave * 16 + lc;
      int arow = memb[islot < c ? islot : 0];
      const unsigned char* ap = Fb + (size_t)arow * FB_STRIDE + g * 8;
#pragma unroll
      for (int kk = 0; kk < 10; ++kk) afr[kk] = *(const long*)(ap + kk * 32);
    }
    int iglobr[4]; bool ivalid[4];
    for (int r = 0; r < 4; ++r) {
      int islot = it * 64 + wave * 16 + g * 4 + r;
      ivalid[r] = islot < c;
      iglobr[r] = memb[islot < c ? islot : 0];
    }
    float sp[4] = {}, sa[4] = {};
    for (int jt = 0; jt < nt; ++jt) {
      __syncthreads();
      {
        const int4* src = (const int4*)Fb;
        int4* dst = (int4*)Bs;
#pragma unroll
        for (int t = 0; t < 5; ++t) {
          int e = tid + t * 256;
          int r = e / 20, q = e - r * 20;
          int jslot = jt * 64 + r;
          int grow = memb[jslot < c ? jslot : 0];
          dst[r * 21 + q] = src[(size_t)grow * 20 + q];
        }
      }
      __syncthreads();
      for (int js = 0; js < 4; ++js) {
        float4v acc = {0.f, 0.f, 0.f, 0.f};
        const unsigned char* rowp = Bs + (js * 16 + lc) * LDS_STRIDE + g * 8;
#pragma unroll
        for (int kk = 0; kk < 10; ++kk) {
          long bv = *(const long*)(rowp + kk * 32);
          acc = __builtin_amdgcn_mfma_f32_16x16x32_fp8_fp8(afr[kk], bv, acc, 0, 0, 0);
        }
        int jslot = jt * 64 + js * 16 + lc;
        bool jv = jslot < c;
        int jglob = memb[jslot < c ? jslot : 0];
#pragma unroll
        for (int r = 0; r < 4; ++r) {
          float a = acc[r];
          float e = exp2f(fmaf(a, LOG2E100, -LOG2E100));
          bool ok = jv && ivalid[r] && (jglob != iglobr[r]);
          sp[r] += ok ? e : 0.f;
          sa[r] += ok ? a : 0.f;
        }
      }
    }
    for (int m = 1; m < 16; m <<= 1)
      for (int r = 0; r < 4; ++r) {
        sp[r] += __shfl_xor(sp[r], m, 64);
        sa[r] += __shfl_xor(sa[r], m, 64);
      }
    if (lc == 0)
      for (int r = 0; r < 4; ++r)
        if (ivalid[r]) { sPar[iglobr[r]] = sp[r]; sAar[iglobr[r]] = sa[r]; }
  }
}

// ---------- dense pairwise: sE only (fp8, standalone, branch-free grid) ----------
__global__ __launch_bounds__(256, 2) void pairwise_kernel(
    const unsigned char* __restrict__ Fb, float* __restrict__ partE)
{
  __shared__ __align__(16) unsigned char Bs[64 * LDS_STRIDE];   // 21504 B
  int tid = threadIdx.x;
  int lane = tid & 63, wave = tid >> 6;
  int g = lane >> 4, lc = lane & 15;
  int i0 = blockIdx.x * 128;
  int split = blockIdx.y;
  int jstart = split * JCHUNK;

  long afr[2][10];
  for (int s = 0; s < 2; ++s) {
    const unsigned char* ap =
        Fb + (size_t)(i0 + s * 64 + wave * 16 + lc) * FB_STRIDE + g * 8;
#pragma unroll
    for (int kk = 0; kk < 10; ++kk) afr[s][kk] = *(const long*)(ap + kk * 32);
  }
  float sE[2][4] = {};

  for (int jt = 0; jt < JCHUNK / 64; ++jt) {
    int jb = jstart + jt * 64;
    __syncthreads();
    {
      const int4* src = (const int4*)Fb;
      int4* dst = (int4*)Bs;
#pragma unroll
      for (int t = 0; t < 5; ++t) {
        int e = tid + t * 256;
        int r = e / 20, q = e - r * 20;
        dst[r * 21 + q] = src[(size_t)(jb + r) * 20 + q];
      }
    }
    __syncthreads();
    for (int js = 0; js < 4; ++js) {
      float4v acc0 = {0.f, 0.f, 0.f, 0.f}, acc1 = {0.f, 0.f, 0.f, 0.f};
      const unsigned char* rowp = Bs + (js * 16 + lc) * LDS_STRIDE + g * 8;
#pragma unroll
      for (int kk = 0; kk < 10; ++kk) {
        long bv = *(const long*)(rowp + kk * 32);
        acc0 = __builtin_amdgcn_mfma_f32_16x16x32_fp8_fp8(afr[0][kk], bv, acc0, 0, 0, 0);
        acc1 = __builtin_amdgcn_mfma_f32_16x16x32_fp8_fp8(afr[1][kk], bv, acc1, 0, 0, 0);
      }
#pragma unroll
      for (int s = 0; s < 2; ++s) {
        float4v acc = s ? acc1 : acc0;
        bool dt = (jb == i0 + s * 64) && (js == wave);   // wave-uniform
        if (dt) {
          // diagonal tile: exclude self-pair (can't be reconstructed later
          // without catastrophic cancellation against ~1e-30-scale sums)
#pragma unroll
          for (int r = 0; r < 4; ++r) {
            float e = exp2f(fmaf(acc[r], LOG2E100, -LOG2E100));
            if (lc == g * 4 + r) e = 0.0f;
            sE[s][r] += e;
          }
        } else {
#pragma unroll
          for (int r = 0; r < 4; ++r)
            sE[s][r] += exp2f(fmaf(acc[r], LOG2E100, -LOG2E100));
        }
      }
    }
  }
  for (int m = 1; m < 16; m <<= 1)
#pragma unroll
    for (int s = 0; s < 2; ++s)
#pragma unroll
      for (int r = 0; r < 4; ++r) sE[s][r] += __shfl_xor(sE[s][r], m, 64);
  if (lc == 0)
    for (int s = 0; s < 2; ++s)
      for (int r = 0; r < 4; ++r)
        partE[split * N_ROWS + i0 + s * 64 + wave * 16 + g * 4 + r] = sE[s][r];
}

// ---------- final_a: 32 blocks, coalesced partE combine + per-row mlpp ----------
__global__ __launch_bounds__(256) void final_a_kernel(
    const float* __restrict__ partE, const float* __restrict__ sPar,
    const float* __restrict__ sAar, const int* __restrict__ counts32,
    const int* __restrict__ labels, float* __restrict__ blk)
{
  __shared__ int cnt_s[NG + 1];
  __shared__ float rm[256], rv[256];
  int tid = threadIdx.x;
  int i = blockIdx.x * 256 + tid;
  if (tid <= NG) {
    int c = 0;
    for (int s = 0; s < 32; ++s) c += counts32[s * (NG + 1) + tid];
    cnt_s[tid] = c;
  }
  float sE = 0.f;
  for (int s = 0; s < NSPLIT; ++s) sE += partE[s * N_ROWS + i];   // coalesced
  __syncthreads();
  float M = 0.f, V = 0.f;
  int pc = cnt_s[labels[i]] - 1;
  if (pc > 0) {
    float P = sPar[i], A = sAar[i];
    float Q = sE - P;
    float pcf = (float)pc, ncf = (float)(N_ROWS - 1 - pc);
    float Z = P / pcf + Q / ncf;
    M = 100.0f * A / pcf - 100.0f - logf(pcf) - logf(Z);
    V = 1.f;
  }
  rm[tid] = M; rv[tid] = V;
  __syncthreads();
  for (int s2 = 128; s2 > 0; s2 >>= 1) {
    if (tid < s2) { rm[tid] += rm[tid + s2]; rv[tid] += rv[tid + s2]; }
    __syncthreads();
  }
  if (tid == 0) { blk[blockIdx.x] = rm[0]; blk[32 + blockIdx.x] = rv[0]; }
}

__global__ void final_b_kernel(const float* __restrict__ blk, float* __restrict__ out)
{
  int lane = threadIdx.x;   // 64 threads
  float m = (lane < 32) ? blk[lane] : 0.f;
  float v = (lane < 32) ? blk[32 + lane] : 0.f;
  for (int s = 1; s < 32; s <<= 1) { m += __shfl_xor(m, s, 64); v += __shfl_xor(v, s, 64); }
  if (lane == 0) out[0] = (v > 0.f) ? (-TEMP * m / v) : 0.f;
}

extern "C" void kernel_launch(void* const* d_in, const int* in_sizes, int n_in,
                              void* d_out, int out_size, void* d_ws, size_t ws_size,
                              hipStream_t stream)
{
  const float* x  = (const float*)d_in[0];
  const float* W1 = (const float*)d_in[1];
  const float* b1 = (const float*)d_in[2];
  const float* W2 = (const float*)d_in[3];
  const float* b2 = (const float*)d_in[4];
  const int* labels = (const int*)d_in[5];

  char* ws = (char*)d_ws;
  unsigned char*  fb    = (unsigned char*)(ws);             // 8192*320 = 2,621,440
  __hip_bfloat16* w1t   = (__hip_bfloat16*)(ws + 2621440);  // 204,800
  __hip_bfloat16* w2t   = (__hip_bfloat16*)(ws + 2826240);  // 204,800
  int*         counts32 = (int*)(ws + 3031040);             // 12,928 (pad 13,056)
  float*        partE   = (float*)(ws + 3044096);           // 1,048,576
  float*        sPar    = (float*)(ws + 4092672);           // 32,768
  float*        sAar    = (float*)(ws + 4125440);           // 32,768
  float*        blk     = (float*)(ws + 4158208);           // 256

  setup_kernel<<<82, 256, 0, stream>>>(W1, W2, labels, w1t, w2t, counts32);
  mlp_fused_kernel<<<512, 256, 0, stream>>>(x, w1t, w2t, b1, b2, fb);
  group_kernel<<<dim3(NG, 2), 256, 0, stream>>>(fb, labels, sPar, sAar);
  pairwise_kernel<<<dim3(64, NSPLIT), 256, 0, stream>>>(fb, partE);
  final_a_kernel<<<32, 256, 0, stream>>>(partE, sPar, sAar, counts32, labels, blk);
  final_b_kernel<<<1, 64, 0, stream>>>(blk, (float*)d_out);
}